// Round 2
// baseline (4134.522 us; speedup 1.0000x reference)
//
#include <hip/hip_runtime.h>
#include <cmath>

#define HH 256
#define WW 256
#define TT 48
#define PLANE (HH * WW * TT)

#if defined(__has_builtin)
#if __has_builtin(__builtin_amdgcn_exp2f)
#define EXP2F(x) __builtin_amdgcn_exp2f(x)
#else
#define EXP2F(x) exp2f(x)
#endif
#else
#define EXP2F(x) exp2f(x)
#endif

#define NEGBIG (-3.0e38f)
#define SKIPT  (-25.0f)   // w = 2^arg < 3e-8 below this; den>=1 -> output err < 4e-5

union F4 { float4 v; float f[4]; };
union F2 { float2 v; float f[2]; };

// Thread owns 2 x-columns x 4 t-centers. Block: 16 xw * 12 tg = 192 threads,
// covering a 32x x 48t tile at one y. Grid: (W/32, H).
__global__ __launch_bounds__(192, 2)
void stat_denoise(const float* __restrict__ images,
                  const float* __restrict__ guidance,
                  const float* __restrict__ estimands,
                  const float* __restrict__ variance,
                  const float* __restrict__ sigma_inv,
                  const int* __restrict__ spp_ptr,
                  float* __restrict__ out)
{
    const int tid = threadIdx.x;
    const int tg  = tid % 12;
    const int xw  = tid / 12;
    const int y   = blockIdx.y;
    const int xA  = (int)blockIdx.x * 32 + 2 * xw;
    const int t0  = tg * 4;

    const float sppf = (float)(*spp_ptr);
    const float T2f  = 2.8070337683438042f * 2.8070337683438042f;
    const float squ  = sqrtf(2.0f * sppf);
    const float L2E  = 1.4426950408889634f;

    float sq[9];
#pragma unroll
    for (int g = 0; g < 9; ++g) sq[g] = sqrtf(sigma_inv[g] * L2E);

    // center guidance: cg = 2*sq*g (doubled for the dot), cc = sum (sq*g)^2
    float cg[9][2][4];
    float cc[2][4] = {};
#pragma unroll
    for (int xs = 0; xs < 2; ++xs) {
        const int cb = (y * WW + xA + xs) * TT + t0;
#pragma unroll
        for (int g = 0; g < 9; ++g) {
            F4 a; a.v = *(const float4*)(guidance + (size_t)g * PLANE + cb);
#pragma unroll
            for (int r = 0; r < 4; ++r) {
                const float s = sq[g] * a.f[r];
                cc[xs][r] = fmaf(s, s, cc[xs][r]);
                cg[g][xs][r] = 2.0f * s;
            }
        }
    }

    float num[3][2][4] = {};
    float den[2][4] = {};

    // neighbor-window t validity: window index k -> t = t0 + k - 2
    bool tval[8];
#pragma unroll
    for (int k = 0; k < 8; ++k) {
        const int tn = t0 + k - 2;
        tval[k] = (tn >= 0) && (tn < TT);
    }
    const int lo = max(t0 - 2, 0);        // b64 load (clamped; masked via tval)
    const int hi = min(t0 + 4, TT - 2);   // b64 load (clamped; masked via tval)

    for (int dy = -3; dy <= 3; ++dy) {
        const int yy  = y + dy;
        const int ycl = min(max(yy, 0), HH - 1);
        const bool yok = (yy == ycl);
        for (int j = 0; j < 8; ++j) {     // neighbor col = xA - 3 + j
            const int xx  = xA - 3 + j;
            const int xcl = min(max(xx, 0), WW - 1);
            const bool cok = yok && (xx == xcl);
            const bool vx0 = cok && (j != 7);   // serves center A (dx in -3..3)
            const bool vx1 = cok && (j != 0);   // serves center B
            const size_t nb = (size_t)(ycl * WW + xcl) * TT;

            // ---- phase A: guidance-only, dots + nn ----
            float dots[2][4][5] = {};
            float nn[8] = {};
#pragma unroll
            for (int g = 0; g < 9; ++g) {
                const float* base = guidance + (size_t)g * PLANE + nb;
                F4 m; m.v = *(const float4*)(base + t0);
                F2 l; l.v = *(const float2*)(base + lo);
                F2 h; h.v = *(const float2*)(base + hi);
                const float w8[8] = { l.f[0], l.f[1], m.f[0], m.f[1],
                                      m.f[2], m.f[3], h.f[0], h.f[1] };
                float ng[8];
#pragma unroll
                for (int k = 0; k < 8; ++k) {
                    ng[k] = sq[g] * w8[k];
                    nn[k] = fmaf(ng[k], ng[k], nn[k]);
                }
#pragma unroll
                for (int xs = 0; xs < 2; ++xs)
#pragma unroll
                    for (int r = 0; r < 4; ++r)
#pragma unroll
                        for (int d = 0; d < 5; ++d)
                            dots[xs][r][d] = fmaf(ng[r + d], cg[g][xs][r], dots[xs][r][d]);
            }

            // finalize args (in place), track colmax
            float colmax = NEGBIG;
#pragma unroll
            for (int xs = 0; xs < 2; ++xs)
#pragma unroll
                for (int r = 0; r < 4; ++r)
#pragma unroll
                    for (int d = 0; d < 5; ++d) {
                        float a = dots[xs][r][d] - nn[r + d] - cc[xs][r];
                        const bool v = (xs == 0 ? vx0 : vx1) && tval[r + d];
                        a = v ? a : NEGBIG;
                        dots[xs][r][d] = a;
                        colmax = fmaxf(colmax, a);
                    }

            if (__any(colmax > SKIPT)) {
                // ---- hit path (rare): z-test + accumulate ----
                float cu[3][2][4], cq[3][2][4];
#pragma unroll
                for (int xs = 0; xs < 2; ++xs) {
                    const int cb = (y * WW + xA + xs) * TT + t0;
#pragma unroll
                    for (int c = 0; c < 3; ++c) {
                        F4 e;  e.v  = *(const float4*)(estimands + (size_t)c * PLANE + cb);
                        F4 vv; vv.v = *(const float4*)(variance  + (size_t)c * PLANE + cb);
#pragma unroll
                        for (int r = 0; r < 4; ++r) {
                            cu[c][xs][r] = squ * e.f[r];
                            cq[c][xs][r] = fmaf(sppf * e.f[r], e.f[r], -T2f * vv.f[r]);
                        }
                    }
                }
                float macc[2][4][5];
#pragma unroll
                for (int c = 0; c < 3; ++c) {
                    const float* be = estimands + (size_t)c * PLANE + nb;
                    const float* bv = variance  + (size_t)c * PLANE + nb;
                    F4 me; me.v = *(const float4*)(be + t0);
                    F2 le; le.v = *(const float2*)(be + lo);
                    F2 he; he.v = *(const float2*)(be + hi);
                    F4 mv; mv.v = *(const float4*)(bv + t0);
                    F2 lv; lv.v = *(const float2*)(bv + lo);
                    F2 hv; hv.v = *(const float2*)(bv + hi);
                    const float e8[8] = { le.f[0], le.f[1], me.f[0], me.f[1],
                                          me.f[2], me.f[3], he.f[0], he.f[1] };
                    const float v8[8] = { lv.f[0], lv.f[1], mv.f[0], mv.f[1],
                                          mv.f[2], mv.f[3], hv.f[0], hv.f[1] };
                    float nu[8], nq[8];
#pragma unroll
                    for (int k = 0; k < 8; ++k) {
                        nu[k] = squ * e8[k];
                        nq[k] = fmaf(sppf * e8[k], e8[k], -T2f * v8[k]);
                    }
#pragma unroll
                    for (int xs = 0; xs < 2; ++xs)
#pragma unroll
                        for (int r = 0; r < 4; ++r)
#pragma unroll
                            for (int d = 0; d < 5; ++d) {
                                const float t = fmaf(-nu[r + d], cu[c][xs][r],
                                                     nq[r + d] + cq[c][xs][r]);
                                macc[xs][r][d] = (c == 0) ? t : fmaxf(macc[xs][r][d], t);
                            }
                }
                // weights (invalid pairs have arg = NEGBIG -> w = 0)
#pragma unroll
                for (int xs = 0; xs < 2; ++xs)
#pragma unroll
                    for (int r = 0; r < 4; ++r)
#pragma unroll
                        for (int d = 0; d < 5; ++d) {
                            float w = EXP2F(dots[xs][r][d]);
                            w = (macc[xs][r][d] <= 0.0f) ? w : 0.0f;
                            dots[xs][r][d] = w;   // reuse as wgt
                            den[xs][r] += w;
                        }
#pragma unroll
                for (int c = 0; c < 3; ++c) {
                    const float* bi = images + (size_t)c * PLANE + nb;
                    F4 mi; mi.v = *(const float4*)(bi + t0);
                    F2 li; li.v = *(const float2*)(bi + lo);
                    F2 hh; hh.v = *(const float2*)(bi + hi);
                    const float i8[8] = { li.f[0], li.f[1], mi.f[0], mi.f[1],
                                          mi.f[2], mi.f[3], hh.f[0], hh.f[1] };
#pragma unroll
                    for (int xs = 0; xs < 2; ++xs)
#pragma unroll
                        for (int r = 0; r < 4; ++r)
#pragma unroll
                            for (int d = 0; d < 5; ++d)
                                num[c][xs][r] = fmaf(dots[xs][r][d], i8[r + d], num[c][xs][r]);
                }
            }
        }
    }

#pragma unroll
    for (int xs = 0; xs < 2; ++xs) {
        const int cb = (y * WW + xA + xs) * TT + t0;
        float rc[4];
#pragma unroll
        for (int r = 0; r < 4; ++r) rc[r] = 1.0f / den[xs][r];
#pragma unroll
        for (int c = 0; c < 3; ++c) {
            F4 o;
#pragma unroll
            for (int r = 0; r < 4; ++r) o.f[r] = num[c][xs][r] * rc[r];
            *(float4*)(out + (size_t)c * PLANE + cb) = o.v;
        }
    }
}

extern "C" void kernel_launch(void* const* d_in, const int* in_sizes, int n_in,
                              void* d_out, int out_size, void* d_ws, size_t ws_size,
                              hipStream_t stream)
{
    (void)in_sizes; (void)n_in; (void)out_size; (void)d_ws; (void)ws_size;
    const float* images    = (const float*)d_in[0];
    const float* guidance  = (const float*)d_in[1];
    const float* estimands = (const float*)d_in[2];
    const float* variance  = (const float*)d_in[3];
    const float* sigma_inv = (const float*)d_in[4];
    const int*   spp       = (const int*)d_in[5];

    dim3 grid(WW / 32, HH, 1);
    dim3 block(192, 1, 1);
    hipLaunchKernelGGL(stat_denoise, grid, block, 0, stream,
                       images, guidance, estimands, variance, sigma_inv, spp,
                       (float*)d_out);
}

// Round 3
// 2651.754 us; speedup vs baseline: 1.5592x; 1.5592x over previous
//
#include <hip/hip_runtime.h>
#include <cmath>

#define HH 256
#define WW 256
#define TT 48
#define PLANE (HH * WW * TT)

#if defined(__has_builtin)
#if __has_builtin(__builtin_amdgcn_exp2f)
#define EXP2F(x) __builtin_amdgcn_exp2f(x)
#else
#define EXP2F(x) exp2f(x)
#endif
#else
#define EXP2F(x) exp2f(x)
#endif

union F4 { float4 v; float f[4]; };
union F2 { float2 v; float f[2]; };

// Thread owns 1 x-column x 4 t-centers. Block: 16 x * 12 tg = 192 threads.
// Grid: (W/16, H).
// Phase 1 (always): conservative joint gate = big-3 guidance distance bound
//   AND z-test (with slack) -> one float score per pair, wave-vote.
// Phase 2 (fired taps only, ~3/wave incl. the always-firing self tap):
//   exact recompute + accumulate.  OOB pad pairs handled analytically in den init.
__global__ __launch_bounds__(192, 3)
void stat_denoise(const float* __restrict__ images,
                  const float* __restrict__ guidance,
                  const float* __restrict__ estimands,
                  const float* __restrict__ variance,
                  const float* __restrict__ sigma_inv,
                  const int* __restrict__ spp_ptr,
                  float* __restrict__ out)
{
    const int tid = threadIdx.x;
    const int tg  = tid % 12;
    const int xl  = tid / 12;
    const int x   = (int)blockIdx.x * 16 + xl;
    const int y   = (int)blockIdx.y;
    const int t0  = tg * 4;

    const float sppf = (float)(*spp_ptr);
    const float T2f  = 2.8070337683438042f * 2.8070337683438042f;
    const float squ  = sqrtf(2.0f * sppf);
    const float L2E  = 1.4426950408889634f;

    float sq[9];
#pragma unroll
    for (int g = 0; g < 9; ++g) sq[g] = sqrtf(sigma_inv[g] * L2E);

    const int cbase = (y * WW + x) * TT + t0;

    // ---- center setup ----
    float cg2[3][4];          // 2*sq*g for prefilter channels 3..5 (dot form)
    float cc3m[4] = {};       // (sum big3 (sq g)^2) - 25
    float ccF[4]  = {};       // full 9-channel norm (pad weight, exp2 units)
#pragma unroll
    for (int g = 0; g < 9; ++g) {
        F4 a; a.v = *(const float4*)(guidance + (size_t)g * PLANE + cbase);
#pragma unroll
        for (int r = 0; r < 4; ++r) {
            const float s = sq[g] * a.f[r];
            ccF[r] = fmaf(s, s, ccF[r]);
            if (g >= 3 && g < 6) {
                cc3m[r] = fmaf(s, s, cc3m[r]);
                cg2[g - 3][r] = 2.0f * s;
            }
        }
    }
#pragma unroll
    for (int r = 0; r < 4; ++r) cc3m[r] -= 25.0f;

    float cu[3][4], cq01[3][4];
    bool okpad[4] = {true, true, true, true};
#pragma unroll
    for (int c = 0; c < 3; ++c) {
        F4 e;  e.v  = *(const float4*)(estimands + (size_t)c * PLANE + cbase);
        F4 vv; vv.v = *(const float4*)(variance  + (size_t)c * PLANE + cbase);
#pragma unroll
        for (int r = 0; r < 4; ++r) {
            const float ec = e.f[r], vc = vv.f[r];
            cu[c][r]   = squ * ec;
            cq01[c][r] = 0.01f - fmaf(sppf * ec, ec, -T2f * vc);
            const float dd = -2.0f - ec;            // pad en = -2, vn = 0
            okpad[r] = okpad[r] && ((dd * dd) * sppf <= T2f * vc);
        }
    }

    // analytic pad contribution: den += n_oob * w_pad * ok_pad; num += 0 (img pad = 0)
    const int cnty = 7 - max(0, 3 - y) - max(0, y + 3 - (HH - 1));
    const int cntx = 7 - max(0, 3 - x) - max(0, x + 3 - (WW - 1));
    float den[4], num[3][4] = {};
#pragma unroll
    for (int r = 0; r < 4; ++r) {
        const int t = t0 + r;
        const int cntt = 5 - max(0, 2 - t) - max(0, t + 2 - (TT - 1));
        const float n_oob = (float)(245 - cnty * cntx * cntt);
        den[r] = okpad[r] ? n_oob * EXP2F(-ccF[r]) : 0.0f;
    }

    bool tval[8];
#pragma unroll
    for (int k = 0; k < 8; ++k) {
        const int tn = t0 + k - 2;
        tval[k] = (tn >= 0) && (tn < TT);
    }
    const int lo = max(t0 - 2, 0);        // 8B-aligned (t0-2 even)
    const int hi = min(t0 + 4, TT - 2);

#pragma unroll 1
    for (int dy = -3; dy <= 3; ++dy) {
        const int yy  = y + dy;
        const int ycl = min(max(yy, 0), HH - 1);
        const bool yok = (yy == ycl);
#pragma unroll 1
        for (int j = 0; j < 7; ++j) {
            const int xx  = x + j - 3;
            const int xcl = min(max(xx, 0), WW - 1);
            const bool cok = yok && (xx == xcl);
            const size_t nb = (size_t)(ycl * WW + xcl) * TT;

            // ===== phase 1: gate score per pair =====
            float sp[4][5] = {};
            float nn3[8] = {};
#pragma unroll
            for (int gi = 0; gi < 3; ++gi) {
                const float* base = guidance + (size_t)(gi + 3) * PLANE + nb;
                F4 m; m.v = *(const float4*)(base + t0);
                F2 l; l.v = *(const float2*)(base + lo);
                F2 h; h.v = *(const float2*)(base + hi);
                const float w8[8] = { l.f[0], l.f[1], m.f[0], m.f[1],
                                      m.f[2], m.f[3], h.f[0], h.f[1] };
                const float s = sq[gi + 3];
                float ng[8];
#pragma unroll
                for (int k = 0; k < 8; ++k) {
                    ng[k] = s * w8[k];
                    nn3[k] = fmaf(ng[k], ng[k], nn3[k]);
                }
#pragma unroll
                for (int r = 0; r < 4; ++r)
#pragma unroll
                    for (int d = 0; d < 5; ++d)
                        sp[r][d] = fmaf(ng[r + d], cg2[gi][r], sp[r][d]);
            }
            // sp = 25 - dist3  (>=0 iff big3 distance bound passes)
#pragma unroll
            for (int r = 0; r < 4; ++r)
#pragma unroll
                for (int d = 0; d < 5; ++d)
                    sp[r][d] -= nn3[r + d] + cc3m[r];
            // sp = min(sp, 0.01 - m_c) over the 3 z-test channels
#pragma unroll
            for (int c = 0; c < 3; ++c) {
                const float* be = estimands + (size_t)c * PLANE + nb;
                const float* bv = variance  + (size_t)c * PLANE + nb;
                F4 me; me.v = *(const float4*)(be + t0);
                F2 le; le.v = *(const float2*)(be + lo);
                F2 he; he.v = *(const float2*)(be + hi);
                F4 mv; mv.v = *(const float4*)(bv + t0);
                F2 lv; lv.v = *(const float2*)(bv + lo);
                F2 hv; hv.v = *(const float2*)(bv + hi);
                const float e8[8] = { le.f[0], le.f[1], me.f[0], me.f[1],
                                      me.f[2], me.f[3], he.f[0], he.f[1] };
                const float v8[8] = { lv.f[0], lv.f[1], mv.f[0], mv.f[1],
                                      mv.f[2], mv.f[3], hv.f[0], hv.f[1] };
                float nu[8], nq[8];
#pragma unroll
                for (int k = 0; k < 8; ++k) {
                    nu[k] = squ * e8[k];
                    nq[k] = fmaf(sppf * e8[k], e8[k], -T2f * v8[k]);
                }
#pragma unroll
                for (int r = 0; r < 4; ++r)
#pragma unroll
                    for (int d = 0; d < 5; ++d) {
                        const float a2 = cq01[c][r] - nq[r + d];
                        sp[r][d] = fminf(sp[r][d], fmaf(nu[r + d], cu[c][r], a2));
                    }
            }
            float rmax = -1.0f;
#pragma unroll
            for (int r = 0; r < 4; ++r)
#pragma unroll
                for (int d = 0; d < 5; ++d) {
                    const bool valid = cok && tval[r + d];
                    rmax = fmaxf(rmax, valid ? sp[r][d] : -1.0f);
                }

            if (__any(rmax >= 0.0f)) {
                // ===== phase 2: exact recompute of this tap =====
                float csg[9][4], ce[3][4], cv[3][4];
#pragma unroll
                for (int g = 0; g < 9; ++g) {
                    F4 a; a.v = *(const float4*)(guidance + (size_t)g * PLANE + cbase);
#pragma unroll
                    for (int r = 0; r < 4; ++r) csg[g][r] = sq[g] * a.f[r];
                }
#pragma unroll
                for (int c = 0; c < 3; ++c) {
                    F4 e;  e.v  = *(const float4*)(estimands + (size_t)c * PLANE + cbase);
                    F4 vv; vv.v = *(const float4*)(variance  + (size_t)c * PLANE + cbase);
#pragma unroll
                    for (int r = 0; r < 4; ++r) { ce[c][r] = e.f[r]; cv[c][r] = vv.f[r]; }
                }
#pragma unroll
                for (int k = 0; k < 8; ++k) {
                    const int tcl = min(max(t0 + k - 2, 0), TT - 1);
                    const bool tv = cok && tval[k];
                    float sgn[9], en[3], vn[3], im[3];
#pragma unroll
                    for (int g = 0; g < 9; ++g)
                        sgn[g] = sq[g] * guidance[(size_t)g * PLANE + nb + tcl];
#pragma unroll
                    for (int c = 0; c < 3; ++c) {
                        en[c] = estimands[(size_t)c * PLANE + nb + tcl];
                        vn[c] = variance [(size_t)c * PLANE + nb + tcl];
                        im[c] = images   [(size_t)c * PLANE + nb + tcl];
                    }
#pragma unroll
                    for (int d = 0; d < 5; ++d) {
                        const int r = k - d;
                        if (r < 0 || r > 3) continue;
                        float dist = 0.0f;
#pragma unroll
                        for (int g = 0; g < 9; ++g) {
                            const float df = sgn[g] - csg[g][r];
                            dist = fmaf(df, df, dist);
                        }
                        const float w = EXP2F(-dist);
                        bool pass = tv;
#pragma unroll
                        for (int c = 0; c < 3; ++c) {
                            const float dd = en[c] - ce[c][r];
                            pass = pass && ((dd * dd) * sppf <= T2f * (vn[c] + cv[c][r]));
                        }
                        const float wgt = pass ? w : 0.0f;
                        den[r] += wgt;
#pragma unroll
                        for (int c = 0; c < 3; ++c)
                            num[c][r] = fmaf(wgt, im[c], num[c][r]);
                    }
                }
            }
        }
    }

    float rc[4];
#pragma unroll
    for (int r = 0; r < 4; ++r) rc[r] = 1.0f / den[r];
#pragma unroll
    for (int c = 0; c < 3; ++c) {
        F4 o;
#pragma unroll
        for (int r = 0; r < 4; ++r) o.f[r] = num[c][r] * rc[r];
        *(float4*)(out + (size_t)c * PLANE + cbase) = o.v;
    }
}

extern "C" void kernel_launch(void* const* d_in, const int* in_sizes, int n_in,
                              void* d_out, int out_size, void* d_ws, size_t ws_size,
                              hipStream_t stream)
{
    (void)in_sizes; (void)n_in; (void)out_size; (void)d_ws; (void)ws_size;
    const float* images    = (const float*)d_in[0];
    const float* guidance  = (const float*)d_in[1];
    const float* estimands = (const float*)d_in[2];
    const float* variance  = (const float*)d_in[3];
    const float* sigma_inv = (const float*)d_in[4];
    const int*   spp       = (const int*)d_in[5];

    dim3 grid(WW / 16, HH, 1);
    dim3 block(192, 1, 1);
    hipLaunchKernelGGL(stat_denoise, grid, block, 0, stream,
                       images, guidance, estimands, variance, sigma_inv, spp,
                       (float*)d_out);
}

// Round 4
// 1541.315 us; speedup vs baseline: 2.6825x; 1.7204x over previous
//
#include <hip/hip_runtime.h>
#include <hip/hip_fp16.h>
#include <cmath>

#define HH 256
#define WW 256
#define TT 48
#define PLANE (HH * WW * TT)

#if defined(__has_builtin)
#if __has_builtin(__builtin_amdgcn_exp2f)
#define EXP2F(x) __builtin_amdgcn_exp2f(x)
#else
#define EXP2F(x) exp2f(x)
#endif
#else
#define EXP2F(x) exp2f(x)
#endif

typedef _Float16 half8 __attribute__((ext_vector_type(8)));
union F4 { float4 v; float f[4]; };

// ---------------- prep: pack gate stream ----------------
// pk[pixel] = {sg3, sg4, sg5, r6, nu0, nu1, q0, q1}  (fp16, 16B)
//   sg_c = sqrt(sig_c*log2e)*g_c (c=3,4,5);  r6 = ||sg|| over channels {0,1,2,6,7,8}
//   nu_c = sqrt(2*spp)*e_c (c=0,1);          q_c = spp*e^2 - T2*v (c=0,1)
__global__ __launch_bounds__(256)
void prep_pack(const float* __restrict__ guidance,
               const float* __restrict__ estimands,
               const float* __restrict__ variance,
               const float* __restrict__ sigma_inv,
               const int* __restrict__ spp_ptr,
               half8* __restrict__ pk)
{
    const int idx = ((int)blockIdx.x * 256 + (int)threadIdx.x) * 4;
    const float sppf = (float)(*spp_ptr);
    const float T2f  = 2.8070337683438042f * 2.8070337683438042f;
    const float squ  = sqrtf(2.0f * sppf);
    const float L2E  = 1.4426950408889634f;
    float sq[9];
#pragma unroll
    for (int g = 0; g < 9; ++g) sq[g] = sqrtf(sigma_inv[g] * L2E);

    F4 gg[9];
#pragma unroll
    for (int g = 0; g < 9; ++g) gg[g].v = *(const float4*)(guidance + (size_t)g * PLANE + idx);
    F4 e0, e1, v0, v1;
    e0.v = *(const float4*)(estimands + 0 * (size_t)PLANE + idx);
    e1.v = *(const float4*)(estimands + 1 * (size_t)PLANE + idx);
    v0.v = *(const float4*)(variance  + 0 * (size_t)PLANE + idx);
    v1.v = *(const float4*)(variance  + 1 * (size_t)PLANE + idx);

#pragma unroll
    for (int s = 0; s < 4; ++s) {
        float r6sq = 0.0f;
#pragma unroll
        for (int g = 0; g < 9; ++g) {
            if (g >= 3 && g < 6) continue;
            const float t = sq[g] * gg[g].f[s];
            r6sq = fmaf(t, t, r6sq);
        }
        half8 h;
        h[0] = (_Float16)(sq[3] * gg[3].f[s]);
        h[1] = (_Float16)(sq[4] * gg[4].f[s]);
        h[2] = (_Float16)(sq[5] * gg[5].f[s]);
        h[3] = (_Float16)sqrtf(r6sq);
        h[4] = (_Float16)(squ * e0.f[s]);
        h[5] = (_Float16)(squ * e1.f[s]);
        h[6] = (_Float16)fmaf(sppf * e0.f[s], e0.f[s], -T2f * v0.f[s]);
        h[7] = (_Float16)fmaf(sppf * e1.f[s], e1.f[s], -T2f * v1.f[s]);
        pk[idx + s] = h;
    }
}

// ---------------- main ----------------
// Thread owns 1 x-column x 8 t-centers. Block: 32 x * 6 tg = 192, grid (W/32, H).
__global__ __launch_bounds__(192, 3)
void stat_denoise(const float* __restrict__ images,
                  const float* __restrict__ guidance,
                  const float* __restrict__ estimands,
                  const float* __restrict__ variance,
                  const float* __restrict__ sigma_inv,
                  const int* __restrict__ spp_ptr,
                  const half8* __restrict__ pk,
                  float* __restrict__ out)
{
    __shared__ float acc[192 * 33];           // 32 slots/thread, stride 33 (bank-conflict-free)
    const int tid = threadIdx.x;
    const int tg  = tid % 6;
    const int xl  = tid / 6;
    const int x   = (int)blockIdx.x * 32 + xl;
    const int y   = (int)blockIdx.y;
    const int t0  = tg * 8;
    float* A = acc + tid * 33;
#pragma unroll
    for (int i = 0; i < 32; ++i) A[i] = 0.0f;

    const float sppf = (float)(*spp_ptr);
    const float T2f  = 2.8070337683438042f * 2.8070337683438042f;
    const float squ  = sqrtf(2.0f * sppf);
    const float L2E  = 1.4426950408889634f;
    float sq[9];
#pragma unroll
    for (int g = 0; g < 9; ++g) sq[g] = sqrtf(sigma_inv[g] * L2E);

    const int ccol  = (y * WW + x) * TT;
    const int cbase = ccol + t0;

    // center gate quantities (exact fp32)
    float csg[3][8], cr6[8], den_extra[8];
    float cnu2[2][8], cqe[2][8];
    {
        float ccF[8] = {};
        float r6sq[8] = {};
#pragma unroll
        for (int g = 0; g < 9; ++g) {
            F4 a, b;
            a.v = *(const float4*)(guidance + (size_t)g * PLANE + cbase);
            b.v = *(const float4*)(guidance + (size_t)g * PLANE + cbase + 4);
#pragma unroll
            for (int r = 0; r < 8; ++r) {
                const float s = sq[g] * (r < 4 ? a.f[r] : b.f[r - 4]);
                ccF[r] = fmaf(s, s, ccF[r]);
                if (g >= 3 && g < 6) csg[g - 3][r] = s;
                else                 r6sq[r] = fmaf(s, s, r6sq[r]);
            }
        }
#pragma unroll
        for (int r = 0; r < 8; ++r) cr6[r] = sqrtf(r6sq[r]);

        bool okpad[8] = {true, true, true, true, true, true, true, true};
#pragma unroll
        for (int c = 0; c < 3; ++c) {
            F4 ea, eb, va, vb;
            ea.v = *(const float4*)(estimands + (size_t)c * PLANE + cbase);
            eb.v = *(const float4*)(estimands + (size_t)c * PLANE + cbase + 4);
            va.v = *(const float4*)(variance  + (size_t)c * PLANE + cbase);
            vb.v = *(const float4*)(variance  + (size_t)c * PLANE + cbase + 4);
#pragma unroll
            for (int r = 0; r < 8; ++r) {
                const float ec = (r < 4 ? ea.f[r] : eb.f[r - 4]);
                const float vc = (r < 4 ? va.f[r] : vb.f[r - 4]);
                if (c < 2) {
                    cnu2[c][r] = 2.0f * squ * ec;                       // 2*nu_c
                    cqe[c][r]  = 1.5f - fmaf(sppf * ec, ec, -T2f * vc); // 1.5 - q_c
                }
                const float dd = -2.0f - ec;                            // pad en=-2, vn=0
                okpad[r] = okpad[r] && ((dd * dd) * sppf <= T2f * vc);
            }
        }
        const int cnty = 7 - max(0, 3 - y) - max(0, y + 3 - (HH - 1));
        const int cntx = 7 - max(0, 3 - x) - max(0, x + 3 - (WW - 1));
#pragma unroll
        for (int r = 0; r < 8; ++r) {
            const int t = t0 + r;
            const int cntt = 5 - max(0, 2 - t) - max(0, t + 2 - (TT - 1));
            const float n_oob = (float)(245 - cnty * cntx * cntt);
            den_extra[r] = 1.0f + (okpad[r] ? n_oob * EXP2F(-ccF[r]) : 0.0f); // +1 = self pair
        }
    }

    // t-window bookkeeping: slot k -> t = t0 - 2 + k, k in [0,12)
    int tcl[12];
    unsigned tvm = 0;
#pragma unroll
    for (int k = 0; k < 12; ++k) {
        const int t = t0 - 2 + k;
        tcl[k] = min(max(t, 0), TT - 1);
        tvm |= ((unsigned)(t >= 0 && t < TT)) << k;
    }

    const float DC = 26.5f;   // 25 (w<2^-25 drop) + fp16 slack

    for (int dy = -3; dy <= 3; ++dy) {
        const int yy  = y + dy;
        const int ycl = min(max(yy, 0), HH - 1);
        const bool yok = (yy == ycl);
        for (int j = 0; j < 7; ++j) {
            const int xx  = x + j - 3;
            const int xcl = min(max(xx, 0), WW - 1);
            const bool cok = yok && (xx == xcl);
            const int nco = (ycl * WW + xcl) * TT;
            const half8* base = pk + nco;

            unsigned mask0 = 0, mask1 = 0;
#pragma unroll
            for (int k = 0; k < 12; ++k) {
                const half8 h = base[tcl[k]];
                const bool vk = cok && ((tvm >> k) & 1u);
                const float ns3 = (float)h[0];
                const float ns4 = (float)h[1];
                const float ns5 = (float)h[2];
                const float nr6 = vk ? (float)h[3] : 3.0e4f;   // poison -> dm << 0
                const float nu0 = (float)h[4];
                const float nu1 = (float)h[5];
                const float nq0 = (float)h[6];
                const float nq1 = (float)h[7];
#pragma unroll
                for (int r = 0; r < 8; ++r) {
                    const int d = k - r;
                    if (d < 0 || d > 4) continue;
                    float d0 = ns3 - csg[0][r];
                    float d1 = ns4 - csg[1][r];
                    float d2 = ns5 - csg[2][r];
                    float dist3 = d0 * d0;
                    dist3 = fmaf(d1, d1, dist3);
                    dist3 = fmaf(d2, d2, dist3);
                    const float dr = nr6 - cr6[r];
                    const float dm = DC - fmaf(dr, dr, dist3);
                    const float p0 = nu0 * cnu2[0][r];
                    const float mz0 = fmaf(0.002f, fabsf(p0), p0 + cqe[0][r]) - nq0;
                    const float p1 = nu1 * cnu2[1][r];
                    const float mz1 = fmaf(0.002f, fabsf(p1), p1 + cqe[1][r]) - nq1;
                    const float m = fminf(dm, fminf(mz0, mz1));
                    const int idx = r * 5 + d;
                    if (idx < 20) mask0 |= (m >= 0.0f) ? (1u << idx) : 0u;
                    else          mask1 |= (m >= 0.0f) ? (1u << (idx - 20)) : 0u;
                }
            }
            if (dy == 0 && j == 3) {      // self pairs (d==2) handled analytically
                mask0 &= ~0x21084u;
                mask1 &= ~0x21084u;
            }

            unsigned long long mm = ((unsigned long long)mask1 << 20) | (unsigned long long)mask0;
            if (mm) {
                do {
                    const int idx = (int)__builtin_ctzll(mm);
                    mm &= mm - 1;
                    const int r  = (idx * 13) >> 6;     // idx/5 for idx<40
                    const int d  = idx - r * 5;
                    const int tc = t0 + r;
                    const int tn = tc + d - 2;
                    // exact recompute of this pair
                    float dist = 0.0f;
#pragma unroll
                    for (int g = 0; g < 9; ++g) {
                        const float gn = guidance[(size_t)g * PLANE + nco + tn];
                        const float gc = guidance[(size_t)g * PLANE + ccol + tc];
                        const float df = sq[g] * (gn - gc);
                        dist = fmaf(df, df, dist);
                    }
                    bool pass = true;
#pragma unroll
                    for (int c = 0; c < 3; ++c) {
                        const float en = estimands[(size_t)c * PLANE + nco + tn];
                        const float ec = estimands[(size_t)c * PLANE + ccol + tc];
                        const float vn = variance [(size_t)c * PLANE + nco + tn];
                        const float vc = variance [(size_t)c * PLANE + ccol + tc];
                        const float de = en - ec;
                        pass = pass && ((de * de) * sppf <= T2f * (vn + vc));
                    }
                    const float w = pass ? EXP2F(-dist) : 0.0f;
                    float* Ar = A + r * 4;
                    Ar[3] += w;
#pragma unroll
                    for (int c = 0; c < 3; ++c)
                        Ar[c] = fmaf(w, images[(size_t)c * PLANE + nco + tn], Ar[c]);
                } while (mm);
            }
        }
    }

    // epilogue: out = (num + img_center) / (den + den_extra)
    F4 ia[3], ib[3];
#pragma unroll
    for (int c = 0; c < 3; ++c) {
        ia[c].v = *(const float4*)(images + (size_t)c * PLANE + cbase);
        ib[c].v = *(const float4*)(images + (size_t)c * PLANE + cbase + 4);
    }
    float rcd[8];
#pragma unroll
    for (int r = 0; r < 8; ++r) rcd[r] = 1.0f / (A[r * 4 + 3] + den_extra[r]);
#pragma unroll
    for (int c = 0; c < 3; ++c) {
        F4 oa, ob;
#pragma unroll
        for (int r = 0; r < 8; ++r) {
            const float ic = (r < 4 ? ia[c].f[r] : ib[c].f[r - 4]);
            const float o  = (A[r * 4 + c] + ic) * rcd[r];
            if (r < 4) oa.f[r] = o; else ob.f[r - 4] = o;
        }
        *(float4*)(out + (size_t)c * PLANE + cbase)     = oa.v;
        *(float4*)(out + (size_t)c * PLANE + cbase + 4) = ob.v;
    }
}

extern "C" void kernel_launch(void* const* d_in, const int* in_sizes, int n_in,
                              void* d_out, int out_size, void* d_ws, size_t ws_size,
                              hipStream_t stream)
{
    (void)in_sizes; (void)n_in; (void)out_size; (void)ws_size;
    const float* images    = (const float*)d_in[0];
    const float* guidance  = (const float*)d_in[1];
    const float* estimands = (const float*)d_in[2];
    const float* variance  = (const float*)d_in[3];
    const float* sigma_inv = (const float*)d_in[4];
    const int*   spp       = (const int*)d_in[5];
    half8* pk = (half8*)d_ws;                       // PLANE * 16 B = 50.3 MB

    hipLaunchKernelGGL(prep_pack, dim3(PLANE / 1024), dim3(256), 0, stream,
                       guidance, estimands, variance, sigma_inv, spp, pk);
    hipLaunchKernelGGL(stat_denoise, dim3(WW / 32, HH), dim3(192), 0, stream,
                       images, guidance, estimands, variance, sigma_inv, spp, pk,
                       (float*)d_out);
}